// Round 19
// baseline (219.153 us; speedup 1.0000x reference)
//
#include <hip/hip_runtime.h>
#include <math.h>

#define NPIX 12544   // B*H*W = 4*56*56
#define CH   128
#define HEADS 4
#define HD   32
#define KS   7
#define HID  512
#define HH   56
#define WW   56

typedef __attribute__((ext_vector_type(8))) short bf16x8;
typedef __attribute__((ext_vector_type(4))) float f32x4;
typedef unsigned short u16;

__device__ inline float gelu_f(float x) { return 0.5f * x * (1.0f + erff(x * 0.70710678118654752f)); }

__device__ inline u16 rne_bf16(float x) {
    unsigned u = __float_as_uint(x);
    return (u16)((u + 0x7fffu + ((u >> 16) & 1u)) >> 16);
}
__device__ inline float bf2f(u16 u) {
    return __uint_as_float(((unsigned)u) << 16);
}

// ================= device bodies =================

// LN-fused K=128 GEMM body: A f32 [M][128] (layernormed inline), Bt bf16 [N][128].
// BM=64, BN in {64,128}, 4 waves. Uses 16KB + BN*128B of sh.
// MODE 1: bf16 = gelu(acc+bias) ; MODE 3: bf16 = acc+bias
template<int BN, int MODE>
__device__ __forceinline__ void qln_body(char* sh,
    const float* __restrict__ Af, const u16* __restrict__ Bt,
    const float* __restrict__ lng, const float* __restrict__ lnb,
    const float* __restrict__ bias, u16* __restrict__ Cb,
    int N, int bx, int by)
{
    constexpr int NF = BN / 32;
    char* alsb = sh;            // 64 rows x 256B, swizzled
    char* blsb = sh + 16384;    // BN rows x 128B, swizzled
    int t = threadIdx.x, lane = t & 63, w = t >> 6;
    int m0 = bx * 64, n0 = by * BN;
    int wr = w >> 1, wc = w & 1;

    {
        int rb = t >> 3, c8 = t & 7;
        float4 va[2][4];
        float sum[2], sq[2];
#pragma unroll
        for (int r2 = 0; r2 < 2; ++r2) {
            int row = r2 * 32 + rb;
            const float4* ap = reinterpret_cast<const float4*>(Af + (size_t)(m0 + row) * 128);
            va[r2][0] = ap[c8 * 2];
            va[r2][1] = ap[c8 * 2 + 1];
            va[r2][2] = ap[16 + c8 * 2];
            va[r2][3] = ap[16 + c8 * 2 + 1];
            float s = 0.f, q = 0.f;
#pragma unroll
            for (int e = 0; e < 4; ++e) {
                float4 x = va[r2][e];
                s += x.x + x.y + x.z + x.w;
                q += x.x * x.x + x.y * x.y + x.z * x.z + x.w * x.w;
            }
            sum[r2] = s; sq[r2] = q;
        }
#pragma unroll
        for (int o = 1; o < 8; o <<= 1) {
            sum[0] += __shfl_xor(sum[0], o); sq[0] += __shfl_xor(sq[0], o);
            sum[1] += __shfl_xor(sum[1], o); sq[1] += __shfl_xor(sq[1], o);
        }
        const float4* gp = reinterpret_cast<const float4*>(lng);
        const float4* bp = reinterpret_cast<const float4*>(lnb);
        float4 g[4], bb[4];
        g[0] = gp[c8 * 2];      g[1] = gp[c8 * 2 + 1];
        g[2] = gp[16 + c8 * 2]; g[3] = gp[16 + c8 * 2 + 1];
        bb[0] = bp[c8 * 2];      bb[1] = bp[c8 * 2 + 1];
        bb[2] = bp[16 + c8 * 2]; bb[3] = bp[16 + c8 * 2 + 1];
#pragma unroll
        for (int r2 = 0; r2 < 2; ++r2) {
            int row = r2 * 32 + rb;
            float mean = sum[r2] * (1.0f / 128.0f);
            float inv = rsqrtf(sq[r2] * (1.0f / 128.0f) - mean * mean + 1e-5f);
#pragma unroll
            for (int h = 0; h < 2; ++h) {
                float4 x0 = va[r2][h * 2], x1 = va[r2][h * 2 + 1];
                float4 g0 = g[h * 2], g1 = g[h * 2 + 1];
                float4 b0 = bb[h * 2], b1 = bb[h * 2 + 1];
                bf16x8 o;
                o[0] = (short)rne_bf16((x0.x - mean) * inv * g0.x + b0.x);
                o[1] = (short)rne_bf16((x0.y - mean) * inv * g0.y + b0.y);
                o[2] = (short)rne_bf16((x0.z - mean) * inv * g0.z + b0.z);
                o[3] = (short)rne_bf16((x0.w - mean) * inv * g0.w + b0.w);
                o[4] = (short)rne_bf16((x1.x - mean) * inv * g1.x + b1.x);
                o[5] = (short)rne_bf16((x1.y - mean) * inv * g1.y + b1.y);
                o[6] = (short)rne_bf16((x1.z - mean) * inv * g1.z + b1.z);
                o[7] = (short)rne_bf16((x1.w - mean) * inv * g1.w + b1.w);
                int byte = (h * 128 + c8 * 16) ^ ((row & 7) << 4);
                *reinterpret_cast<bf16x8*>(alsb + row * 256 + byte) = o;
            }
        }
    }

    f32x4 acc[2][NF] = {};
    for (int kk = 0; kk < 2; ++kk) {
#pragma unroll
        for (int i = 0; i < BN / 32; ++i) {
            int s = t + i * 256, row = s >> 3, ch = (s & 7) * 8;
            bf16x8 v = *reinterpret_cast<const bf16x8*>(Bt + (size_t)(n0 + row) * 128 + kk * 64 + ch);
            *reinterpret_cast<bf16x8*>(blsb + row * 128 + ((ch * 2) ^ ((row & 7) << 4))) = v;
        }
        __syncthreads();
#pragma unroll
        for (int sub = 0; sub < 2; ++sub) {
            int kba = (kk * 2 + sub) * 64 + (lane >> 4) * 16;
            int kbb = sub * 64 + (lane >> 4) * 16;
            bf16x8 af[2], bfr[NF];
#pragma unroll
            for (int mi = 0; mi < 2; ++mi) {
                int row = wr * 32 + mi * 16 + (lane & 15);
                af[mi] = *reinterpret_cast<const bf16x8*>(alsb + row * 256 + (kba ^ ((row & 7) << 4)));
            }
#pragma unroll
            for (int ni = 0; ni < NF; ++ni) {
                int row = wc * (BN / 2) + ni * 16 + (lane & 15);
                bfr[ni] = *reinterpret_cast<const bf16x8*>(blsb + row * 128 + (kbb ^ ((row & 7) << 4)));
            }
#pragma unroll
            for (int mi = 0; mi < 2; ++mi)
#pragma unroll
                for (int ni = 0; ni < NF; ++ni)
                    acc[mi][ni] = __builtin_amdgcn_mfma_f32_16x16x32_bf16(af[mi], bfr[ni], acc[mi][ni], 0, 0, 0);
        }
        __syncthreads();
    }

    int fq = lane >> 4, fr = lane & 15;
#pragma unroll
    for (int mi = 0; mi < 2; ++mi) {
#pragma unroll
        for (int ni = 0; ni < NF; ++ni) {
            int col = n0 + wc * (BN / 2) + ni * 16 + fr;
            float bv = bias[col];
#pragma unroll
            for (int j = 0; j < 4; ++j) {
                int row = m0 + wr * 32 + mi * 16 + fq * 4 + j;
                float v = acc[mi][ni][j] + bv;
                if constexpr (MODE == 1) {
                    Cb[(size_t)row * N + col] = rne_bf16(gelu_f(v));
                } else {
                    Cb[(size_t)row * N + col] = rne_bf16(v);
                }
            }
        }
    }
}

// k-loop MFMA GEMM body: A bf16 [M][K], Bt bf16 [N][K]. BM=32, BN=64. Uses 12KB of sh.
// MODE 2: f32 = acc+bias+res ; MODE 3: bf16 = acc+bias
template<int MODE>
__device__ __forceinline__ void gemm_body(char* sh,
    const u16* __restrict__ A, const u16* __restrict__ Bt,
    const float* __restrict__ bias, const float* __restrict__ res,
    float* __restrict__ Cf, u16* __restrict__ Cb,
    int N, int K, int bx, int by)
{
    char* alsb = sh;            // 32 rows x 128B
    char* blsb = sh + 4096;     // 64 rows x 128B
    int t = threadIdx.x;
    int m0 = bx * 32, n0 = by * 64;
    int lane = t & 63, w = t >> 6;
    int wr = w >> 1, wc = w & 1;
    f32x4 acc[2] = {};
    for (int k0 = 0; k0 < K; k0 += 64) {
        {
            int s = t, row = s >> 3, ch = (s & 7) * 8;
            bf16x8 v = *reinterpret_cast<const bf16x8*>(A + (size_t)(m0 + row) * K + k0 + ch);
            *reinterpret_cast<bf16x8*>(alsb + row * 128 + ((ch * 2) ^ ((row & 7) << 4))) = v;
        }
#pragma unroll
        for (int i = 0; i < 2; ++i) {
            int s = t + i * 256, row = s >> 3, ch = (s & 7) * 8;
            bf16x8 v = *reinterpret_cast<const bf16x8*>(Bt + (size_t)(n0 + row) * K + k0 + ch);
            *reinterpret_cast<bf16x8*>(blsb + row * 128 + ((ch * 2) ^ ((row & 7) << 4))) = v;
        }
        __syncthreads();
#pragma unroll
        for (int kk = 0; kk < 2; ++kk) {
            int kb = kk * 64 + (lane >> 4) * 16;
            int row_a = wr * 16 + (lane & 15);
            bf16x8 af = *reinterpret_cast<const bf16x8*>(alsb + row_a * 128 + (kb ^ ((row_a & 7) << 4)));
#pragma unroll
            for (int ni = 0; ni < 2; ++ni) {
                int row = wc * 32 + ni * 16 + (lane & 15);
                bf16x8 bfr = *reinterpret_cast<const bf16x8*>(blsb + row * 128 + (kb ^ ((row & 7) << 4)));
                acc[ni] = __builtin_amdgcn_mfma_f32_16x16x32_bf16(af, bfr, acc[ni], 0, 0, 0);
            }
        }
        __syncthreads();
    }
    int fq = lane >> 4, fr = lane & 15;
#pragma unroll
    for (int ni = 0; ni < 2; ++ni) {
        int col = n0 + wc * 32 + ni * 16 + fr;
        float bv = bias[col];
#pragma unroll
        for (int j = 0; j < 4; ++j) {
            int row = m0 + wr * 16 + fq * 4 + j;
            float v = acc[ni][j] + bv;
            if constexpr (MODE == 2) {
                Cf[(size_t)row * N + col] = v + res[(size_t)row * N + col];
            } else {
                Cb[(size_t)row * N + col] = rne_bf16(v);
            }
        }
    }
}

// fc2 body: BM=32, BN=128 (full N in one block), K=512. 4 waves each own 32x32.
// Uses 20KB of sh. f32 res-add + bf16 mirror epilogue.
__device__ __forceinline__ void fc2_body(char* sh,
    const u16* __restrict__ A, const u16* __restrict__ Bt,
    const float* __restrict__ bias, const float* __restrict__ res,
    float* __restrict__ Cf, u16* __restrict__ Cb, int bx)
{
    char* alsb = sh;            // 32 rows x 128B
    char* blsb = sh + 4096;     // 128 rows x 128B
    int t = threadIdx.x, lane = t & 63, w = t >> 6;
    int m0 = bx * 32;
    f32x4 acc[2][2] = {};
    for (int k0 = 0; k0 < 512; k0 += 64) {
        {
            int row = t >> 3, ch = (t & 7) * 8;
            bf16x8 v = *reinterpret_cast<const bf16x8*>(A + (size_t)(m0 + row) * 512 + k0 + ch);
            *reinterpret_cast<bf16x8*>(alsb + row * 128 + ((ch * 2) ^ ((row & 7) << 4))) = v;
        }
#pragma unroll
        for (int i = 0; i < 4; ++i) {
            int s = t + i * 256, row = s >> 3, ch = (s & 7) * 8;
            bf16x8 v = *reinterpret_cast<const bf16x8*>(Bt + (size_t)row * 512 + k0 + ch);
            *reinterpret_cast<bf16x8*>(blsb + row * 128 + ((ch * 2) ^ ((row & 7) << 4))) = v;
        }
        __syncthreads();
#pragma unroll
        for (int kk = 0; kk < 2; ++kk) {
            int kb = kk * 64 + (lane >> 4) * 16;
            bf16x8 af[2], bfr[2];
#pragma unroll
            for (int mi = 0; mi < 2; ++mi) {
                int row_a = mi * 16 + (lane & 15);
                af[mi] = *reinterpret_cast<const bf16x8*>(alsb + row_a * 128 + (kb ^ ((row_a & 7) << 4)));
            }
#pragma unroll
            for (int ni = 0; ni < 2; ++ni) {
                int row = w * 32 + ni * 16 + (lane & 15);
                bfr[ni] = *reinterpret_cast<const bf16x8*>(blsb + row * 128 + (kb ^ ((row & 7) << 4)));
            }
#pragma unroll
            for (int mi = 0; mi < 2; ++mi)
#pragma unroll
                for (int ni = 0; ni < 2; ++ni)
                    acc[mi][ni] = __builtin_amdgcn_mfma_f32_16x16x32_bf16(af[mi], bfr[ni], acc[mi][ni], 0, 0, 0);
        }
        __syncthreads();
    }
    int fq = lane >> 4, fr = lane & 15;
#pragma unroll
    for (int mi = 0; mi < 2; ++mi) {
#pragma unroll
        for (int ni = 0; ni < 2; ++ni) {
            int col = w * 32 + ni * 16 + fr;
            float bv = bias[col];
#pragma unroll
            for (int j = 0; j < 4; ++j) {
                int row = m0 + mi * 16 + fq * 4 + j;
                float r2 = acc[mi][ni][j] + bv + res[(size_t)row * 128 + col];
                Cf[(size_t)row * 128 + col] = r2;
                Cb[(size_t)row * 128 + col] = rne_bf16(r2);
            }
        }
    }
}

// ================= merged kernels =================

struct TDesc { const float* src; u16* dst; int K; int N; int tile0; };
struct TPack { TDesc d[19]; };

// wtrans (blocks 0..ntile-1) + dup (rest; initial f32 xcb copy is dead -> only xb + xcbbf)
__global__ __launch_bounds__(256) void prep_kernel(TPack p, int ntile,
    const float* __restrict__ X, float* __restrict__ o1,
    u16* __restrict__ ob, int n4)
{
    __shared__ float tl[32][33];
    if ((int)blockIdx.x < ntile) {
        int tile = blockIdx.x;
        int i = 0;
#pragma unroll 1
        while (i < 18 && tile >= p.d[i + 1].tile0) ++i;
        TDesc d = p.d[i];
        int local = tile - d.tile0;
        int ktiles = d.K >> 5;
        int lk = local % ktiles, ln_ = local / ktiles;
        int k0 = lk * 32, n0 = ln_ * 32;
        int tx = threadIdx.x & 31, ty = threadIdx.x >> 5;
#pragma unroll
        for (int r = 0; r < 4; ++r) {
            int row = ty * 4 + r;
            tl[row][tx] = d.src[(size_t)(k0 + row) * d.N + n0 + tx];
        }
        __syncthreads();
#pragma unroll
        for (int r = 0; r < 4; ++r) {
            int row = ty * 4 + r;
            d.dst[(size_t)(n0 + row) * d.K + k0 + tx] = rne_bf16(tl[tx][row]);
        }
    } else {
        int i = ((int)blockIdx.x - ntile) * 256 + threadIdx.x;
        if (i < n4) {
            float4 v = reinterpret_cast<const float4*>(X)[i];
            reinterpret_cast<float4*>(o1)[i] = v;
            ushort4 o;
            o.x = rne_bf16(v.x); o.y = rne_bf16(v.y); o.z = rne_bf16(v.z); o.w = rne_bf16(v.w);
            reinterpret_cast<ushort4*>(ob)[i] = o;
        }
    }
}

// SA qkv BN=128 (588) + CR q BN=64 (784) + CR kv BN=128 (392)
__global__ __launch_bounds__(256) void stage1_kernel(
    const float* xb, const u16* qkvt, const float* n1g, const float* n1b, const float* qkvbias, u16* qkvout,
    const u16* xq, const u16* qwt, const float* qbias, u16* qout,
    const float* xm, const u16* kvt, const float* kn1g, const float* kn1b, const float* kvbias, u16* kvout)
{
    __shared__ __align__(16) char sh[32768];
    int b = blockIdx.x;
    if (b < 588) {
        qln_body<128, 3>(sh, xb, qkvt, n1g, n1b, qkvbias, qkvout, 384, b / 3, b % 3);
    } else if (b < 1372) {
        int lb = b - 588;
        gemm_body<3>(sh, xq, qwt, qbias, nullptr, nullptr, qout, 128, 128, lb >> 1, lb & 1);
    } else {
        int lb = b - 1372;
        qln_body<128, 3>(sh, xm, kvt, kn1g, kn1b, kvbias, kvout, 256, lb >> 1, lb & 1);
    }
}

// proj x2 : grid (784,2)
__global__ __launch_bounds__(256) void proj_kernel(
    const u16* Asa, const u16* Bsa, const float* bsa, const float* rsa, float* Csa,
    const u16* Acr, const u16* Bcr, const float* bcr, const float* rcr, float* Ccr)
{
    __shared__ __align__(16) char sh[12288];
    if (blockIdx.x < 392)
        gemm_body<2>(sh, Asa, Bsa, bsa, rsa, Csa, nullptr, 128, 128, blockIdx.x, blockIdx.y);
    else
        gemm_body<2>(sh, Acr, Bcr, bcr, rcr, Ccr, nullptr, 128, 128, blockIdx.x - 392, blockIdx.y);
}

// fc1 x2 : grid (392,4), BN=128
__global__ __launch_bounds__(256) void fc1_kernel(
    const float* Asa, const u16* Bsa, const float* g1, const float* b1, const float* bisa, u16* Csa,
    const float* Acr, const u16* Bcr, const float* g2, const float* b2, const float* bicr, u16* Ccr)
{
    __shared__ __align__(16) char sh[32768];
    if (blockIdx.x < 196)
        qln_body<128, 1>(sh, Asa, Bsa, g1, b1, bisa, Csa, 512, blockIdx.x, blockIdx.y);
    else
        qln_body<128, 1>(sh, Acr, Bcr, g2, b2, bicr, Ccr, 512, blockIdx.x - 196, blockIdx.y);
}

// fc2 x2 : grid 784, BN=128 (A read once, 8 MFMA/barrier-pair)
__global__ __launch_bounds__(256) void fc2_kernel(
    const u16* Asa, const u16* Bsa, const float* bsa, const float* rsa, float* Cfsa, u16* Cbsa,
    const u16* Acr, const u16* Bcr, const float* bcr, const float* rcr, float* Cfcr, u16* Cbcr)
{
    __shared__ __align__(16) char sh[20480];
    if (blockIdx.x < 392)
        fc2_body(sh, Asa, Bsa, bsa, rsa, Cfsa, Cbsa, blockIdx.x);
    else
        fc2_body(sh, Acr, Bcr, bcr, rcr, Cfcr, Cbcr, blockIdx.x - 392);
}

// conv as MFMA implicit GEMM: M=3136 (BM=32), N=512 (BN=64), K=2304
__global__ __launch_bounds__(256) void conv_mfma_kernel(
    const u16* __restrict__ Xb, const u16* __restrict__ Xc,
    const u16* __restrict__ Wt, float* __restrict__ Out)
{
    __shared__ u16 Als[32 * 64];
    __shared__ u16 Bls[64 * 64];
    char* alsb = reinterpret_cast<char*>(Als);
    char* blsb = reinterpret_cast<char*>(Bls);
    int t = threadIdx.x;
    int m0 = blockIdx.x * 32, n0 = blockIdx.y * 64;
    int lane = t & 63, w = t >> 6, wr = w >> 1, wc = w & 1;

    int arow = t >> 3, ach = (t & 7) * 8;
    int pm = m0 + arow;
    int b = pm / 784; int rem = pm - b * 784;
    int oi = rem / 28, oj = rem - oi * 28;
    int pb = b * 56, ib = 2 * oi - 1, jb = 2 * oj - 1;

    f32x4 acc[2] = {};
    for (int k0 = 0; k0 < 2304; k0 += 64) {
        {
            int k = k0 + ach;
            int tap = k >> 8, c = k & 255;
            int ky = (tap * 11) >> 5, kx = tap - ky * 3;
            int ii = ib + ky, jj = jb + kx;
            bf16x8 v = {};
            if ((unsigned)ii < 56u && (unsigned)jj < 56u) {
                const u16* src = (c < 128) ? Xb : Xc;
                v = *reinterpret_cast<const bf16x8*>(src + (size_t)((pb + ii) * 56 + jj) * 128 + (c & 127));
            }
            *reinterpret_cast<bf16x8*>(alsb + arow * 128 + ((ach * 2) ^ ((arow & 7) << 4))) = v;
        }
#pragma unroll
        for (int i = 0; i < 2; ++i) {
            int s = t + i * 256, row = s >> 3, ch = (s & 7) * 8;
            bf16x8 v = *reinterpret_cast<const bf16x8*>(Wt + (size_t)(n0 + row) * 2304 + k0 + ch);
            *reinterpret_cast<bf16x8*>(blsb + row * 128 + ((ch * 2) ^ ((row & 7) << 4))) = v;
        }
        __syncthreads();
#pragma unroll
        for (int kk = 0; kk < 2; ++kk) {
            int kb = kk * 64 + (lane >> 4) * 16;
            int row_a = wr * 16 + (lane & 15);
            bf16x8 af = *reinterpret_cast<const bf16x8*>(alsb + row_a * 128 + (kb ^ ((row_a & 7) << 4)));
#pragma unroll
            for (int ni = 0; ni < 2; ++ni) {
                int row = wc * 32 + ni * 16 + (lane & 15);
                bf16x8 bfr = *reinterpret_cast<const bf16x8*>(blsb + row * 128 + (kb ^ ((row & 7) << 4)));
                acc[ni] = __builtin_amdgcn_mfma_f32_16x16x32_bf16(af, bfr, acc[ni], 0, 0, 0);
            }
        }
        __syncthreads();
    }
    int fq = lane >> 4, fr = lane & 15;
#pragma unroll
    for (int ni = 0; ni < 2; ++ni) {
        int col = n0 + wc * 32 + ni * 16 + fr;
#pragma unroll
        for (int j = 0; j < 4; ++j) {
            int row = m0 + wr * 16 + fq * 4 + j;
            Out[(size_t)row * 512 + col] = acc[ni][j];
        }
    }
}

// MFMA neighborhood attention, merged SA+CR: grid (392, 8); sel = y>>2, h = y&3
// P/Vt [32][160] -> 32.0KB LDS, 5 blocks/CU.
__global__ __launch_bounds__(256) void na2_kernel(
    const u16* __restrict__ Qa, int qlda, const u16* __restrict__ Ka, const u16* __restrict__ Va,
    int kvlda, const float* __restrict__ rpba, u16* __restrict__ Outa,
    const u16* __restrict__ Qb, int qldb, const u16* __restrict__ Kb, const u16* __restrict__ Vb,
    int kvldb, const float* __restrict__ rpbb, u16* __restrict__ Outb)
{
    __shared__ u16 KSls[144 * 40];   // K: 144x40 u16; later S: 32x152 u16 + rls @u16-off 4864
    __shared__ u16 Pls[32 * 160];
    __shared__ u16 Vtls[32 * 160];
    u16* Kls = KSls;
    u16* Sls16 = KSls;
    float* rls = reinterpret_cast<float*>(KSls + 4864);

    int sel = blockIdx.y >> 2;
    const u16* Q  = sel ? Qb : Qa;     int qld  = sel ? qldb : qlda;
    const u16* Kx = sel ? Kb : Ka;     const u16* Vx = sel ? Vb : Va;
    int kvld = sel ? kvldb : kvlda;
    const float* rpb = sel ? rpbb : rpba;
    u16* Out = sel ? Outb : Outa;
    int h = blockIdx.y & 3;

    int t = threadIdx.x, lane = t & 63, w = t >> 6;
    int blk = blockIdx.x;
    int b = blk / 98; int rem = blk - b * 98;
    int ti = rem / 7, tj = rem - ti * 7;
    int i0 = ti * 4, j0 = tj * 8;
    int r0 = min(max(i0 - 3, 0), 46), c0 = min(max(j0 - 3, 0), 42);
    int gbase = (b * 56 + r0) * 56 + c0;

    bf16x8 aq[2];
#pragma unroll
    for (int qt = 0; qt < 2; ++qt) {
        int q = qt * 16 + (lane & 15);
        int qi = q >> 3, qj = q & 7;
        aq[qt] = *reinterpret_cast<const bf16x8*>(
            Q + (size_t)((b * 56 + i0 + qi) * 56 + j0 + qj) * qld + h * 32 + (lane >> 4) * 8);
    }

    {
        uint4 z4 = make_uint4(0, 0, 0, 0);
        for (int i = t; i < 640; i += 256) reinterpret_cast<uint4*>(Pls)[i] = z4;
        if (t < 160) {
            int r = t / 5, k = t - r * 5;
            ushort4 z2; z2.x = 0; z2.y = 0; z2.z = 0; z2.w = 0;
            *reinterpret_cast<ushort4*>(Vtls + r * 160 + 140 + k * 4) = z2;
        }
    }

    for (int idx = t; idx < 280; idx += 256) {
        int pr2 = idx >> 2, c8 = (idx & 3) * 8;
        int p0 = pr2 * 2, p1 = p0 + 1;
        int ur0 = p0 / 14, uc0 = p0 - ur0 * 14;
        int ur1 = p1 / 14, uc1 = p1 - ur1 * 14;
        size_t g0 = (size_t)(gbase + ur0 * 56 + uc0) * kvld + h * 32 + c8;
        size_t g1 = (size_t)(gbase + ur1 * 56 + uc1) * kvld + h * 32 + c8;
        *reinterpret_cast<bf16x8*>(Kls + p0 * 40 + c8) = *reinterpret_cast<const bf16x8*>(Kx + g0);
        *reinterpret_cast<bf16x8*>(Kls + p1 * 40 + c8) = *reinterpret_cast<const bf16x8*>(Kx + g1);
        bf16x8 v0 = *reinterpret_cast<const bf16x8*>(Vx + g0);
        bf16x8 v1 = *reinterpret_cast<const bf16x8*>(Vx + g1);
#pragma unroll
        for (int e = 0; e < 8; ++e) {
            ushort2 pr; pr.x = (u16)v0[e]; pr.y = (u16)v1[e];
            *reinterpret_cast<ushort2*>(Vtls + (c8 + e) * 160 + p0) = pr;
        }
    }
    if (t < 16) {
        int r = 140 + (t >> 2), c8 = (t & 3) * 8;
        bf16x8 z8 = {};
        *reinterpret_cast<bf16x8*>(Kls + r * 40 + c8) = z8;
    }
    __syncthreads();

    f32x4 sacc[3][2] = {};
#pragma unroll
    for (int pi = 0; pi < 3; ++pi) {
        int pt = w + pi * 4;
        if (pt < 9) {
            bf16x8 bfrag = *reinterpret_cast<const bf16x8*>(Kls + (pt * 16 + (lane & 15)) * 40 + (lane >> 4) * 8);
#pragma unroll
            for (int qt = 0; qt < 2; ++qt)
                sacc[pi][qt] = __builtin_amdgcn_mfma_f32_16x16x32_bf16(aq[qt], bfrag, sacc[pi][qt], 0, 0, 0);
        }
    }
    __syncthreads();
#pragma unroll
    for (int pi = 0; pi < 3; ++pi) {
        int pt = w + pi * 4;
        if (pt < 9) {
#pragma unroll
            for (int qt = 0; qt < 2; ++qt) {
                int p = pt * 16 + (lane & 15), qr = qt * 16 + (lane >> 4) * 4;
#pragma unroll
                for (int j = 0; j < 4; ++j) Sls16[(qr + j) * 152 + p] = rne_bf16(sacc[pi][qt][j]);
            }
        }
    }
    if (t < 169) rls[t] = rpb[h * 169 + t];
    __syncthreads();

    int ai = lane / 7, aj = lane - ai * 7;
    for (int qq = 0; qq < 8; ++qq) {
        int q = w * 8 + qq;
        int qi = q >> 3, qj = q & 7;
        int i = i0 + qi, j = j0 + qj;
        int si = min(max(i - 3, 0), 49), sj = min(max(j - 3, 0), 49);
        int pu_base = (si - r0) * 14 + (sj - c0);
        float s = -1e30f; int pu = 0;
        if (lane < 49) {
            pu = pu_base + ai * 14 + aj;
            s = bf2f(Sls16[q * 152 + pu]) * 0.17677669529663687f
              + rls[(si - i + 6 + ai) * 13 + (sj - j + 6 + aj)];
        }
        float m = s;
#pragma unroll
        for (int o = 32; o > 0; o >>= 1) m = fmaxf(m, __shfl_xor(m, o));
        float e = (lane < 49) ? expf(s - m) : 0.f;
        float sum = e;
#pragma unroll
        for (int o = 32; o > 0; o >>= 1) sum += __shfl_xor(sum, o);
        if (lane < 49) Pls[q * 160 + pu] = rne_bf16(e / sum);
    }
    __syncthreads();

    int qt = w >> 1, ct = w & 1;
    f32x4 oacc = {};
#pragma unroll
    for (int k = 0; k < 5; ++k) {
        bf16x8 pa = *reinterpret_cast<const bf16x8*>(Pls + (qt * 16 + (lane & 15)) * 160 + k * 32 + (lane >> 4) * 8);
        bf16x8 vb = *reinterpret_cast<const bf16x8*>(Vtls + (ct * 16 + (lane & 15)) * 160 + k * 32 + (lane >> 4) * 8);
        oacc = __builtin_amdgcn_mfma_f32_16x16x32_bf16(pa, vb, oacc, 0, 0, 0);
    }
    int ch = ct * 16 + (lane & 15);
#pragma unroll
    for (int j = 0; j < 4; ++j) {
        int q = qt * 16 + (lane >> 4) * 4 + j;
        int qi = q >> 3, qj = q & 7;
        Out[(size_t)((b * 56 + i0 + qi) * 56 + j0 + qj) * CH + h * 32 + ch] = rne_bf16(oacc[j]);
    }
}

// final LayerNorm over 512, 4 rows/block, write f32
__global__ __launch_bounds__(256) void ln512_out_kernel(const float* __restrict__ in,
    const float* __restrict__ g, const float* __restrict__ b, float* __restrict__ out)
{
    int w = threadIdx.x >> 6, lane = threadIdx.x & 63;
    int p = blockIdx.x * 4 + w;
    const float4* ip = reinterpret_cast<const float4*>(in + (size_t)p * 512);
    float4 v0 = ip[lane * 2], v1 = ip[lane * 2 + 1];
    float vals[8] = { v0.x, v0.y, v0.z, v0.w, v1.x, v1.y, v1.z, v1.w };
    float s = 0.f, sq = 0.f;
#pragma unroll
    for (int q = 0; q < 8; ++q) { s += vals[q]; sq += vals[q] * vals[q]; }
#pragma unroll
    for (int o = 32; o > 0; o >>= 1) { s += __shfl_xor(s, o); sq += __shfl_xor(sq, o); }
    float mean = s * (1.0f / 512.0f);
    float inv = rsqrtf(sq * (1.0f / 512.0f) - mean * mean + 1e-5f);
#pragma unroll
    for (int q = 0; q < 8; ++q) {
        int c = lane * 8 + q;
        out[(size_t)p * 512 + c] = (vals[q] - mean) * inv * g[c] + b[c];
    }
}

extern "C" void kernel_launch(void* const* d_in, const int* in_sizes, int n_in,
                              void* d_out, int out_size, void* d_ws, size_t ws_size,
                              hipStream_t stream)
{
    const float* X      = (const float*)d_in[0];
    const float* XM     = (const float*)d_in[1];
    const float* sa_n1g = (const float*)d_in[2];
    const float* sa_n1b = (const float*)d_in[3];
    const float* sa_qkvw= (const float*)d_in[4];
    const float* sa_qkvb= (const float*)d_in[5];
    const float* sa_rpb = (const float*)d_in[6];
    const float* sa_pw  = (const float*)d_in[7];
    const float* sa_pb  = (const float*)d_in[8];
    const float* sa_n2g = (const float*)d_in[9];
    const float* sa_n2b = (const float*)d_in[10];
    const float* sa_f1w = (const float*)d_in[11];
    const float* sa_f1b = (const float*)d_in[12];
    const float* sa_f2w = (const float*)d_in[13];
    const float* sa_f2b = (const float*)d_in[14];
    const float* cr_n1g = (const float*)d_in[15];
    const float* cr_n1b = (const float*)d_in[16];
    const float* cr_qw  = (const float*)d_in[17];
    const float* cr_qb  = (const float*)d_in[18];
    const float* cr_kvw = (const float*)d_in[19];
    const float* cr_kvb = (const float*)d_in[20];
    const float* cr_rpb = (const float*)d_in[21];
    const float* cr_pw  = (const float*)d_in[22];
    const float* cr_pb  = (const float*)d_in[23];
    const float* cr_n2g = (const float*)d_in[24];
    const float* cr_n2b = (const float*)d_in[25];
    const float* cr_f1w = (const float*)d_in[26];
    const float* cr_f1b = (const float*)d_in[27];
    const float* cr_f2w = (const float*)d_in[28];
    const float* cr_f2b = (const float*)d_in[29];
    const float* dconvw = (const float*)d_in[30];
    const float* ds_ng  = (const float*)d_in[31];
    const float* ds_nb  = (const float*)d_in[32];

    const size_t NC = (size_t)NPIX * CH;       // 1,605,632
    float* ws   = (float*)d_ws;
    float* xb   = ws;                          // [NPIX,128] f32 x state
    float* xcb  = xb + NC;                     // [NPIX,128] f32 x_cross state (first written by CR proj)
    float* bigR = xcb + NC;                    // 2NC f32 region
    u16* bigb   = (u16*)bigR;                  // [NPIX,512] bf16: CR kv (stage1/NA) then SA fc1 out
    u16* hnb    = (u16*)(bigR + 2 * NC);       // [NPIX,128] bf16: CR NA out
    u16* attnb  = hnb + NC;                    // [NPIX,128] bf16: SA NA out
    u16* xcbbf  = attnb + NC;                  // [NPIX,128] bf16 mirror of xcb state
    u16* xbbf   = xcbbf + NC;                  // [NPIX,128] bf16 mirror of xb (for conv)
    u16* qkvb   = xbbf + NC;                   // [NPIX,384] bf16 SA qkv; with bufQb = CR fc1 out region
    u16* bufQb  = qkvb + (size_t)NPIX * 384;   // [NPIX,128] bf16 CR q
    u16* wa     = bufQb + NC;                  // bf16 weight arena
    u16* kvb    = bigb;                        // [NPIX,256] CR kv (time-disjoint alias)
    u16* bigcr  = qkvb;                        // [NPIX,512] CR fc1 out (time-disjoint alias of qkvb+bufQb)

    // ---- weight arena layout + transpose descriptors ----
    TPack tp;
    int tile = 0, idx = 0;
    u16* p = wa;
    u16* qkvt[2]; u16* pwt[2]; u16* f1t[2]; u16* f2t[2];
    u16* qt[2];   u16* kvt[2]; u16* cpt[2]; u16* cf1t[2];
    u16* cf2t[2]; u16* convt;
    auto add = [&](const float* s, u16*& dst, int K, int N) {
        dst = p;
        tp.d[idx].src = s; tp.d[idx].dst = p; tp.d[idx].K = K; tp.d[idx].N = N; tp.d[idx].tile0 = tile;
        tile += (K / 32) * (N / 32); p += (size_t)K * N; ++idx;
    };
    for (int l = 0; l < 2; ++l) add(sa_qkvw + (size_t)l * 128 * 384, qkvt[l], 128, 384);
    for (int l = 0; l < 2; ++l) add(sa_pw   + (size_t)l * 128 * 128, pwt[l],  128, 128);
    for (int l = 0; l < 2; ++l) add(sa_f1w  + (size_t)l * 128 * 512, f1t[l],  128, 512);
    for (int l = 0; l < 2; ++l) add(sa_f2w  + (size_t)l * 512 * 128, f2t[l],  512, 128);
    for (int l = 0; l < 2; ++l) add(cr_qw   + (size_t)l * 128 * 128, qt[l],   128, 128);
    for (int l = 0; l < 2; ++l) add(cr_kvw  + (size_t)l * 128 * 256, kvt[l],  128, 256);
    for (int l = 0; l < 2; ++l) add(cr_pw   + (size_t)l * 128 * 128, cpt[l],  128, 128);
    for (int l = 0; l < 2; ++l) add(cr_f1w  + (size_t)l * 128 * 512, cf1t[l], 128, 512);
    for (int l = 0; l < 2; ++l) add(cr_f2w  + (size_t)l * 512 * 128, cf2t[l], 512, 128);
    add(dconvw, convt, 2304, 512);

    const int n4 = NPIX * CH / 4;
    const int ndup = (n4 + 255) / 256;
    prep_kernel<<<tile + ndup, 256, 0, stream>>>(tp, tile, X, xb, xcbbf, n4);

    for (int l = 0; l < 2; ++l) {
        stage1_kernel<<<1764, 256, 0, stream>>>(
            xb, qkvt[l], sa_n1g + l * CH, sa_n1b + l * CH, sa_qkvb + l * 384, qkvb,
            xcbbf, qt[l], cr_qb + l * CH, bufQb,
            XM, kvt[l], cr_n1g + l * CH, cr_n1b + l * CH, cr_kvb + l * 256, kvb);
        na2_kernel<<<dim3(392, 8), 256, 0, stream>>>(
            qkvb, 384, qkvb + 128, qkvb + 256, 384, sa_rpb + l * HEADS * 169, attnb,
            bufQb, 128, kvb, kvb + 128, 256, cr_rpb + l * HEADS * 169, hnb);
        proj_kernel<<<dim3(784, 2), 256, 0, stream>>>(
            attnb, pwt[l], sa_pb + l * CH, xb, xb,
            hnb, cpt[l], cr_pb + l * CH, XM, xcb);
        fc1_kernel<<<dim3(392, 4), 256, 0, stream>>>(
            xb, f1t[l], sa_n2g + l * CH, sa_n2b + l * CH, sa_f1b + l * HID, bigb,
            xcb, cf1t[l], cr_n2g + l * CH, cr_n2b + l * CH, cr_f1b + l * HID, bigcr);
        fc2_kernel<<<784, 256, 0, stream>>>(
            bigb, f2t[l], sa_f2b + l * CH, xb, xb, xbbf,
            bigcr, cf2t[l], cr_f2b + l * CH, xcb, xcb, xcbbf);
    }

    // ---- downsample conv (MFMA implicit GEMM) + final LN ----
    conv_mfma_kernel<<<dim3(3136 / 32, 512 / 64), 256, 0, stream>>>(xbbf, xcbbf, convt, bigR);
    ln512_out_kernel<<<3136 / 4, 256, 0, stream>>>(bigR, ds_ng, ds_nb, (float*)d_out);
}

// Round 20
// 215.539 us; speedup vs baseline: 1.0168x; 1.0168x over previous
//
#include <hip/hip_runtime.h>
#include <math.h>

#define NPIX 12544   // B*H*W = 4*56*56
#define CH   128
#define HEADS 4
#define HD   32
#define KS   7
#define HID  512
#define HH   56
#define WW   56

typedef __attribute__((ext_vector_type(8))) short bf16x8;
typedef __attribute__((ext_vector_type(4))) float f32x4;
typedef unsigned short u16;

__device__ inline float gelu_f(float x) { return 0.5f * x * (1.0f + erff(x * 0.70710678118654752f)); }

__device__ inline u16 rne_bf16(float x) {
    unsigned u = __float_as_uint(x);
    return (u16)((u + 0x7fffu + ((u >> 16) & 1u)) >> 16);
}
__device__ inline float bf2f(u16 u) {
    return __uint_as_float(((unsigned)u) << 16);
}

// ================= device bodies =================

// LN-fused K=128 GEMM body: A f32 [M][128] (layernormed inline), Bt bf16 [N][128].
// BM=64, BN in {64,128}, 4 waves. Uses 16KB + BN*128B of sh.
// MODE 1: bf16 = gelu(acc+bias) ; MODE 3: bf16 = acc+bias
template<int BN, int MODE>
__device__ __forceinline__ void qln_body(char* sh,
    const float* __restrict__ Af, const u16* __restrict__ Bt,
    const float* __restrict__ lng, const float* __restrict__ lnb,
    const float* __restrict__ bias, u16* __restrict__ Cb,
    int N, int bx, int by)
{
    constexpr int NF = BN / 32;
    char* alsb = sh;            // 64 rows x 256B, swizzled
    char* blsb = sh + 16384;    // BN rows x 128B, swizzled
    int t = threadIdx.x, lane = t & 63, w = t >> 6;
    int m0 = bx * 64, n0 = by * BN;
    int wr = w >> 1, wc = w & 1;

    {
        int rb = t >> 3, c8 = t & 7;
        float4 va[2][4];
        float sum[2], sq[2];
#pragma unroll
        for (int r2 = 0; r2 < 2; ++r2) {
            int row = r2 * 32 + rb;
            const float4* ap = reinterpret_cast<const float4*>(Af + (size_t)(m0 + row) * 128);
            va[r2][0] = ap[c8 * 2];
            va[r2][1] = ap[c8 * 2 + 1];
            va[r2][2] = ap[16 + c8 * 2];
            va[r2][3] = ap[16 + c8 * 2 + 1];
            float s = 0.f, q = 0.f;
#pragma unroll
            for (int e = 0; e < 4; ++e) {
                float4 x = va[r2][e];
                s += x.x + x.y + x.z + x.w;
                q += x.x * x.x + x.y * x.y + x.z * x.z + x.w * x.w;
            }
            sum[r2] = s; sq[r2] = q;
        }
#pragma unroll
        for (int o = 1; o < 8; o <<= 1) {
            sum[0] += __shfl_xor(sum[0], o); sq[0] += __shfl_xor(sq[0], o);
            sum[1] += __shfl_xor(sum[1], o); sq[1] += __shfl_xor(sq[1], o);
        }
        const float4* gp = reinterpret_cast<const float4*>(lng);
        const float4* bp = reinterpret_cast<const float4*>(lnb);
        float4 g[4], bb[4];
        g[0] = gp[c8 * 2];      g[1] = gp[c8 * 2 + 1];
        g[2] = gp[16 + c8 * 2]; g[3] = gp[16 + c8 * 2 + 1];
        bb[0] = bp[c8 * 2];      bb[1] = bp[c8 * 2 + 1];
        bb[2] = bp[16 + c8 * 2]; bb[3] = bp[16 + c8 * 2 + 1];
#pragma unroll
        for (int r2 = 0; r2 < 2; ++r2) {
            int row = r2 * 32 + rb;
            float mean = sum[r2] * (1.0f / 128.0f);
            float inv = rsqrtf(sq[r2] * (1.0f / 128.0f) - mean * mean + 1e-5f);
#pragma unroll
            for (int h = 0; h < 2; ++h) {
                float4 x0 = va[r2][h * 2], x1 = va[r2][h * 2 + 1];
                float4 g0 = g[h * 2], g1 = g[h * 2 + 1];
                float4 b0 = bb[h * 2], b1 = bb[h * 2 + 1];
                bf16x8 o;
                o[0] = (short)rne_bf16((x0.x - mean) * inv * g0.x + b0.x);
                o[1] = (short)rne_bf16((x0.y - mean) * inv * g0.y + b0.y);
                o[2] = (short)rne_bf16((x0.z - mean) * inv * g0.z + b0.z);
                o[3] = (short)rne_bf16((x0.w - mean) * inv * g0.w + b0.w);
                o[4] = (short)rne_bf16((x1.x - mean) * inv * g1.x + b1.x);
                o[5] = (short)rne_bf16((x1.y - mean) * inv * g1.y + b1.y);
                o[6] = (short)rne_bf16((x1.z - mean) * inv * g1.z + b1.z);
                o[7] = (short)rne_bf16((x1.w - mean) * inv * g1.w + b1.w);
                int byte = (h * 128 + c8 * 16) ^ ((row & 7) << 4);
                *reinterpret_cast<bf16x8*>(alsb + row * 256 + byte) = o;
            }
        }
    }

    f32x4 acc[2][NF] = {};
    for (int kk = 0; kk < 2; ++kk) {
#pragma unroll
        for (int i = 0; i < BN / 32; ++i) {
            int s = t + i * 256, row = s >> 3, ch = (s & 7) * 8;
            bf16x8 v = *reinterpret_cast<const bf16x8*>(Bt + (size_t)(n0 + row) * 128 + kk * 64 + ch);
            *reinterpret_cast<bf16x8*>(blsb + row * 128 + ((ch * 2) ^ ((row & 7) << 4))) = v;
        }
        __syncthreads();
#pragma unroll
        for (int sub = 0; sub < 2; ++sub) {
            int kba = (kk * 2 + sub) * 64 + (lane >> 4) * 16;
            int kbb = sub * 64 + (lane >> 4) * 16;
            bf16x8 af[2], bfr[NF];
#pragma unroll
            for (int mi = 0; mi < 2; ++mi) {
                int row = wr * 32 + mi * 16 + (lane & 15);
                af[mi] = *reinterpret_cast<const bf16x8*>(alsb + row * 256 + (kba ^ ((row & 7) << 4)));
            }
#pragma unroll
            for (int ni = 0; ni < NF; ++ni) {
                int row = wc * (BN / 2) + ni * 16 + (lane & 15);
                bfr[ni] = *reinterpret_cast<const bf16x8*>(blsb + row * 128 + (kbb ^ ((row & 7) << 4)));
            }
#pragma unroll
            for (int mi = 0; mi < 2; ++mi)
#pragma unroll
                for (int ni = 0; ni < NF; ++ni)
                    acc[mi][ni] = __builtin_amdgcn_mfma_f32_16x16x32_bf16(af[mi], bfr[ni], acc[mi][ni], 0, 0, 0);
        }
        __syncthreads();
    }

    int fq = lane >> 4, fr = lane & 15;
#pragma unroll
    for (int mi = 0; mi < 2; ++mi) {
#pragma unroll
        for (int ni = 0; ni < NF; ++ni) {
            int col = n0 + wc * (BN / 2) + ni * 16 + fr;
            float bv = bias[col];
#pragma unroll
            for (int j = 0; j < 4; ++j) {
                int row = m0 + wr * 32 + mi * 16 + fq * 4 + j;
                float v = acc[mi][ni][j] + bv;
                if constexpr (MODE == 1) {
                    Cb[(size_t)row * N + col] = rne_bf16(gelu_f(v));
                } else {
                    Cb[(size_t)row * N + col] = rne_bf16(v);
                }
            }
        }
    }
}

// k-loop MFMA GEMM body: A bf16 [M][K], Bt bf16 [N][K]. BM=32, BN=64. Uses 12KB of sh.
// MODE 2: f32 = acc+bias+res ; MODE 3: bf16 = acc+bias ; MODE 4: f32 res-add + bf16 mirror
template<int MODE>
__device__ __forceinline__ void gemm_body(char* sh,
    const u16* __restrict__ A, const u16* __restrict__ Bt,
    const float* __restrict__ bias, const float* __restrict__ res,
    float* __restrict__ Cf, u16* __restrict__ Cb,
    int N, int K, int bx, int by)
{
    char* alsb = sh;            // 32 rows x 128B
    char* blsb = sh + 4096;     // 64 rows x 128B
    int t = threadIdx.x;
    int m0 = bx * 32, n0 = by * 64;
    int lane = t & 63, w = t >> 6;
    int wr = w >> 1, wc = w & 1;
    f32x4 acc[2] = {};
    for (int k0 = 0; k0 < K; k0 += 64) {
        {
            int s = t, row = s >> 3, ch = (s & 7) * 8;
            bf16x8 v = *reinterpret_cast<const bf16x8*>(A + (size_t)(m0 + row) * K + k0 + ch);
            *reinterpret_cast<bf16x8*>(alsb + row * 128 + ((ch * 2) ^ ((row & 7) << 4))) = v;
        }
#pragma unroll
        for (int i = 0; i < 2; ++i) {
            int s = t + i * 256, row = s >> 3, ch = (s & 7) * 8;
            bf16x8 v = *reinterpret_cast<const bf16x8*>(Bt + (size_t)(n0 + row) * K + k0 + ch);
            *reinterpret_cast<bf16x8*>(blsb + row * 128 + ((ch * 2) ^ ((row & 7) << 4))) = v;
        }
        __syncthreads();
#pragma unroll
        for (int kk = 0; kk < 2; ++kk) {
            int kb = kk * 64 + (lane >> 4) * 16;
            int row_a = wr * 16 + (lane & 15);
            bf16x8 af = *reinterpret_cast<const bf16x8*>(alsb + row_a * 128 + (kb ^ ((row_a & 7) << 4)));
#pragma unroll
            for (int ni = 0; ni < 2; ++ni) {
                int row = wc * 32 + ni * 16 + (lane & 15);
                bf16x8 bfr = *reinterpret_cast<const bf16x8*>(blsb + row * 128 + (kb ^ ((row & 7) << 4)));
                acc[ni] = __builtin_amdgcn_mfma_f32_16x16x32_bf16(af, bfr, acc[ni], 0, 0, 0);
            }
        }
        __syncthreads();
    }
    int fq = lane >> 4, fr = lane & 15;
#pragma unroll
    for (int ni = 0; ni < 2; ++ni) {
        int col = n0 + wc * 32 + ni * 16 + fr;
        float bv = bias[col];
#pragma unroll
        for (int j = 0; j < 4; ++j) {
            int row = m0 + wr * 16 + fq * 4 + j;
            float v = acc[ni][j] + bv;
            if constexpr (MODE == 2) {
                Cf[(size_t)row * N + col] = v + res[(size_t)row * N + col];
            } else if constexpr (MODE == 3) {
                Cb[(size_t)row * N + col] = rne_bf16(v);
            } else {
                float r2 = v + res[(size_t)row * N + col];
                Cf[(size_t)row * N + col] = r2;
                Cb[(size_t)row * N + col] = rne_bf16(r2);
            }
        }
    }
}

// ================= merged kernels =================

struct TDesc { const float* src; u16* dst; int K; int N; int tile0; };
struct TPack { TDesc d[19]; };

// wtrans (blocks 0..ntile-1) + dup (rest; initial f32 xcb copy is dead -> only xb + xcbbf)
__global__ __launch_bounds__(256) void prep_kernel(TPack p, int ntile,
    const float* __restrict__ X, float* __restrict__ o1,
    u16* __restrict__ ob, int n4)
{
    __shared__ float tl[32][33];
    if ((int)blockIdx.x < ntile) {
        int tile = blockIdx.x;
        int i = 0;
#pragma unroll 1
        while (i < 18 && tile >= p.d[i + 1].tile0) ++i;
        TDesc d = p.d[i];
        int local = tile - d.tile0;
        int ktiles = d.K >> 5;
        int lk = local % ktiles, ln_ = local / ktiles;
        int k0 = lk * 32, n0 = ln_ * 32;
        int tx = threadIdx.x & 31, ty = threadIdx.x >> 5;
#pragma unroll
        for (int r = 0; r < 4; ++r) {
            int row = ty * 4 + r;
            tl[row][tx] = d.src[(size_t)(k0 + row) * d.N + n0 + tx];
        }
        __syncthreads();
#pragma unroll
        for (int r = 0; r < 4; ++r) {
            int row = ty * 4 + r;
            d.dst[(size_t)(n0 + row) * d.K + k0 + tx] = rne_bf16(tl[tx][row]);
        }
    } else {
        int i = ((int)blockIdx.x - ntile) * 256 + threadIdx.x;
        if (i < n4) {
            float4 v = reinterpret_cast<const float4*>(X)[i];
            reinterpret_cast<float4*>(o1)[i] = v;
            ushort4 o;
            o.x = rne_bf16(v.x); o.y = rne_bf16(v.y); o.z = rne_bf16(v.z); o.w = rne_bf16(v.w);
            reinterpret_cast<ushort4*>(ob)[i] = o;
        }
    }
}

// SA qkv BN=128 (588) + CR q BN=64 (784) + CR kv BN=128 (392)
__global__ __launch_bounds__(256) void stage1_kernel(
    const float* xb, const u16* qkvt, const float* n1g, const float* n1b, const float* qkvbias, u16* qkvout,
    const u16* xq, const u16* qwt, const float* qbias, u16* qout,
    const float* xm, const u16* kvt, const float* kn1g, const float* kn1b, const float* kvbias, u16* kvout)
{
    __shared__ __align__(16) char sh[32768];
    int b = blockIdx.x;
    if (b < 588) {
        qln_body<128, 3>(sh, xb, qkvt, n1g, n1b, qkvbias, qkvout, 384, b / 3, b % 3);
    } else if (b < 1372) {
        int lb = b - 588;
        gemm_body<3>(sh, xq, qwt, qbias, nullptr, nullptr, qout, 128, 128, lb >> 1, lb & 1);
    } else {
        int lb = b - 1372;
        qln_body<128, 3>(sh, xm, kvt, kn1g, kn1b, kvbias, kvout, 256, lb >> 1, lb & 1);
    }
}

// proj x2 : grid (784,2)
__global__ __launch_bounds__(256) void proj_kernel(
    const u16* Asa, const u16* Bsa, const float* bsa, const float* rsa, float* Csa,
    const u16* Acr, const u16* Bcr, const float* bcr, const float* rcr, float* Ccr)
{
    __shared__ __align__(16) char sh[12288];
    if (blockIdx.x < 392)
        gemm_body<2>(sh, Asa, Bsa, bsa, rsa, Csa, nullptr, 128, 128, blockIdx.x, blockIdx.y);
    else
        gemm_body<2>(sh, Acr, Bcr, bcr, rcr, Ccr, nullptr, 128, 128, blockIdx.x - 392, blockIdx.y);
}

// fc1 x2 : grid (392,4), BN=128
__global__ __launch_bounds__(256) void fc1_kernel(
    const float* Asa, const u16* Bsa, const float* g1, const float* b1, const float* bisa, u16* Csa,
    const float* Acr, const u16* Bcr, const float* g2, const float* b2, const float* bicr, u16* Ccr)
{
    __shared__ __align__(16) char sh[32768];
    if (blockIdx.x < 196)
        qln_body<128, 1>(sh, Asa, Bsa, g1, b1, bisa, Csa, 512, blockIdx.x, blockIdx.y);
    else
        qln_body<128, 1>(sh, Acr, Bcr, g2, b2, bicr, Ccr, 512, blockIdx.x - 196, blockIdx.y);
}

// fc2 x2 : grid (784,2)  (reverted to round-18 proven shape)
__global__ __launch_bounds__(256) void fc2_kernel(
    const u16* Asa, const u16* Bsa, const float* bsa, const float* rsa, float* Cfsa, u16* Cbsa,
    const u16* Acr, const u16* Bcr, const float* bcr, const float* rcr, float* Cfcr, u16* Cbcr)
{
    __shared__ __align__(16) char sh[12288];
    if (blockIdx.x < 392)
        gemm_body<4>(sh, Asa, Bsa, bsa, rsa, Cfsa, Cbsa, 128, 512, blockIdx.x, blockIdx.y);
    else
        gemm_body<4>(sh, Acr, Bcr, bcr, rcr, Cfcr, Cbcr, 128, 512, blockIdx.x - 392, blockIdx.y);
}

// conv as MFMA implicit GEMM: M=3136 (BM=32), N=512 (BN=64), K=2304
__global__ __launch_bounds__(256) void conv_mfma_kernel(
    const u16* __restrict__ Xb, const u16* __restrict__ Xc,
    const u16* __restrict__ Wt, float* __restrict__ Out)
{
    __shared__ u16 Als[32 * 64];
    __shared__ u16 Bls[64 * 64];
    char* alsb = reinterpret_cast<char*>(Als);
    char* blsb = reinterpret_cast<char*>(Bls);
    int t = threadIdx.x;
    int m0 = blockIdx.x * 32, n0 = blockIdx.y * 64;
    int lane = t & 63, w = t >> 6, wr = w >> 1, wc = w & 1;

    int arow = t >> 3, ach = (t & 7) * 8;
    int pm = m0 + arow;
    int b = pm / 784; int rem = pm - b * 784;
    int oi = rem / 28, oj = rem - oi * 28;
    int pb = b * 56, ib = 2 * oi - 1, jb = 2 * oj - 1;

    f32x4 acc[2] = {};
    for (int k0 = 0; k0 < 2304; k0 += 64) {
        {
            int k = k0 + ach;
            int tap = k >> 8, c = k & 255;
            int ky = (tap * 11) >> 5, kx = tap - ky * 3;
            int ii = ib + ky, jj = jb + kx;
            bf16x8 v = {};
            if ((unsigned)ii < 56u && (unsigned)jj < 56u) {
                const u16* src = (c < 128) ? Xb : Xc;
                v = *reinterpret_cast<const bf16x8*>(src + (size_t)((pb + ii) * 56 + jj) * 128 + (c & 127));
            }
            *reinterpret_cast<bf16x8*>(alsb + arow * 128 + ((ach * 2) ^ ((arow & 7) << 4))) = v;
        }
#pragma unroll
        for (int i = 0; i < 2; ++i) {
            int s = t + i * 256, row = s >> 3, ch = (s & 7) * 8;
            bf16x8 v = *reinterpret_cast<const bf16x8*>(Wt + (size_t)(n0 + row) * 2304 + k0 + ch);
            *reinterpret_cast<bf16x8*>(blsb + row * 128 + ((ch * 2) ^ ((row & 7) << 4))) = v;
        }
        __syncthreads();
#pragma unroll
        for (int kk = 0; kk < 2; ++kk) {
            int kb = kk * 64 + (lane >> 4) * 16;
            int row_a = wr * 16 + (lane & 15);
            bf16x8 af = *reinterpret_cast<const bf16x8*>(alsb + row_a * 128 + (kb ^ ((row_a & 7) << 4)));
#pragma unroll
            for (int ni = 0; ni < 2; ++ni) {
                int row = wc * 32 + ni * 16 + (lane & 15);
                bf16x8 bfr = *reinterpret_cast<const bf16x8*>(blsb + row * 128 + (kb ^ ((row & 7) << 4)));
                acc[ni] = __builtin_amdgcn_mfma_f32_16x16x32_bf16(af, bfr, acc[ni], 0, 0, 0);
            }
        }
        __syncthreads();
    }
    int fq = lane >> 4, fr = lane & 15;
#pragma unroll
    for (int ni = 0; ni < 2; ++ni) {
        int col = n0 + wc * 32 + ni * 16 + fr;
#pragma unroll
        for (int j = 0; j < 4; ++j) {
            int row = m0 + wr * 16 + fq * 4 + j;
            Out[(size_t)row * 512 + col] = acc[ni][j];
        }
    }
}

// MFMA neighborhood attention, merged SA+CR: grid (392, 8); sel = y>>2, h = y&3
// P/Vt [32][160] -> 32.0KB LDS, 5 blocks/CU.
__global__ __launch_bounds__(256) void na2_kernel(
    const u16* __restrict__ Qa, int qlda, const u16* __restrict__ Ka, const u16* __restrict__ Va,
    int kvlda, const float* __restrict__ rpba, u16* __restrict__ Outa,
    const u16* __restrict__ Qb, int qldb, const u16* __restrict__ Kb, const u16* __restrict__ Vb,
    int kvldb, const float* __restrict__ rpbb, u16* __restrict__ Outb)
{
    __shared__ u16 KSls[144 * 40];   // K: 144x40 u16; later S: 32x152 u16 + rls @u16-off 4864
    __shared__ u16 Pls[32 * 160];
    __shared__ u16 Vtls[32 * 160];
    u16* Kls = KSls;
    u16* Sls16 = KSls;
    float* rls = reinterpret_cast<float*>(KSls + 4864);

    int sel = blockIdx.y >> 2;
    const u16* Q  = sel ? Qb : Qa;     int qld  = sel ? qldb : qlda;
    const u16* Kx = sel ? Kb : Ka;     const u16* Vx = sel ? Vb : Va;
    int kvld = sel ? kvldb : kvlda;
    const float* rpb = sel ? rpbb : rpba;
    u16* Out = sel ? Outb : Outa;
    int h = blockIdx.y & 3;

    int t = threadIdx.x, lane = t & 63, w = t >> 6;
    int blk = blockIdx.x;
    int b = blk / 98; int rem = blk - b * 98;
    int ti = rem / 7, tj = rem - ti * 7;
    int i0 = ti * 4, j0 = tj * 8;
    int r0 = min(max(i0 - 3, 0), 46), c0 = min(max(j0 - 3, 0), 42);
    int gbase = (b * 56 + r0) * 56 + c0;

    bf16x8 aq[2];
#pragma unroll
    for (int qt = 0; qt < 2; ++qt) {
        int q = qt * 16 + (lane & 15);
        int qi = q >> 3, qj = q & 7;
        aq[qt] = *reinterpret_cast<const bf16x8*>(
            Q + (size_t)((b * 56 + i0 + qi) * 56 + j0 + qj) * qld + h * 32 + (lane >> 4) * 8);
    }

    {
        uint4 z4 = make_uint4(0, 0, 0, 0);
        for (int i = t; i < 640; i += 256) reinterpret_cast<uint4*>(Pls)[i] = z4;
        if (t < 160) {
            int r = t / 5, k = t - r * 5;
            ushort4 z2; z2.x = 0; z2.y = 0; z2.z = 0; z2.w = 0;
            *reinterpret_cast<ushort4*>(Vtls + r * 160 + 140 + k * 4) = z2;
        }
    }

    for (int idx = t; idx < 280; idx += 256) {
        int pr2 = idx >> 2, c8 = (idx & 3) * 8;
        int p0 = pr2 * 2, p1 = p0 + 1;
        int ur0 = p0 / 14, uc0 = p0 - ur0 * 14;
        int ur1 = p1 / 14, uc1 = p1 - ur1 * 14;
        size_t g0 = (size_t)(gbase + ur0 * 56 + uc0) * kvld + h * 32 + c8;
        size_t g1 = (size_t)(gbase + ur1 * 56 + uc1) * kvld + h * 32 + c8;
        *reinterpret_cast<bf16x8*>(Kls + p0 * 40 + c8) = *reinterpret_cast<const bf16x8*>(Kx + g0);
        *reinterpret_cast<bf16x8*>(Kls + p1 * 40 + c8) = *reinterpret_cast<const bf16x8*>(Kx + g1);
        bf16x8 v0 = *reinterpret_cast<const bf16x8*>(Vx + g0);
        bf16x8 v1 = *reinterpret_cast<const bf16x8*>(Vx + g1);
#pragma unroll
        for (int e = 0; e < 8; ++e) {
            ushort2 pr; pr.x = (u16)v0[e]; pr.y = (u16)v1[e];
            *reinterpret_cast<ushort2*>(Vtls + (c8 + e) * 160 + p0) = pr;
        }
    }
    if (t < 16) {
        int r = 140 + (t >> 2), c8 = (t & 3) * 8;
        bf16x8 z8 = {};
        *reinterpret_cast<bf16x8*>(Kls + r * 40 + c8) = z8;
    }
    __syncthreads();

    f32x4 sacc[3][2] = {};
#pragma unroll
    for (int pi = 0; pi < 3; ++pi) {
        int pt = w + pi * 4;
        if (pt < 9) {
            bf16x8 bfrag = *reinterpret_cast<const bf16x8*>(Kls + (pt * 16 + (lane & 15)) * 40 + (lane >> 4) * 8);
#pragma unroll
            for (int qt = 0; qt < 2; ++qt)
                sacc[pi][qt] = __builtin_amdgcn_mfma_f32_16x16x32_bf16(aq[qt], bfrag, sacc[pi][qt], 0, 0, 0);
        }
    }
    __syncthreads();
#pragma unroll
    for (int pi = 0; pi < 3; ++pi) {
        int pt = w + pi * 4;
        if (pt < 9) {
#pragma unroll
            for (int qt = 0; qt < 2; ++qt) {
                int p = pt * 16 + (lane & 15), qr = qt * 16 + (lane >> 4) * 4;
#pragma unroll
                for (int j = 0; j < 4; ++j) Sls16[(qr + j) * 152 + p] = rne_bf16(sacc[pi][qt][j]);
            }
        }
    }
    if (t < 169) rls[t] = rpb[h * 169 + t];
    __syncthreads();

    int ai = lane / 7, aj = lane - ai * 7;
    for (int qq = 0; qq < 8; ++qq) {
        int q = w * 8 + qq;
        int qi = q >> 3, qj = q & 7;
        int i = i0 + qi, j = j0 + qj;
        int si = min(max(i - 3, 0), 49), sj = min(max(j - 3, 0), 49);
        int pu_base = (si - r0) * 14 + (sj - c0);
        float s = -1e30f; int pu = 0;
        if (lane < 49) {
            pu = pu_base + ai * 14 + aj;
            s = bf2f(Sls16[q * 152 + pu]) * 0.17677669529663687f
              + rls[(si - i + 6 + ai) * 13 + (sj - j + 6 + aj)];
        }
        float m = s;
#pragma unroll
        for (int o = 32; o > 0; o >>= 1) m = fmaxf(m, __shfl_xor(m, o));
        float e = (lane < 49) ? expf(s - m) : 0.f;
        float sum = e;
#pragma unroll
        for (int o = 32; o > 0; o >>= 1) sum += __shfl_xor(sum, o);
        if (lane < 49) Pls[q * 160 + pu] = rne_bf16(e / sum);
    }
    __syncthreads();

    int qt = w >> 1, ct = w & 1;
    f32x4 oacc = {};
#pragma unroll
    for (int k = 0; k < 5; ++k) {
        bf16x8 pa = *reinterpret_cast<const bf16x8*>(Pls + (qt * 16 + (lane & 15)) * 160 + k * 32 + (lane >> 4) * 8);
        bf16x8 vb = *reinterpret_cast<const bf16x8*>(Vtls + (ct * 16 + (lane & 15)) * 160 + k * 32 + (lane >> 4) * 8);
        oacc = __builtin_amdgcn_mfma_f32_16x16x32_bf16(pa, vb, oacc, 0, 0, 0);
    }
    int ch = ct * 16 + (lane & 15);
#pragma unroll
    for (int j = 0; j < 4; ++j) {
        int q = qt * 16 + (lane >> 4) * 4 + j;
        int qi = q >> 3, qj = q & 7;
        Out[(size_t)((b * 56 + i0 + qi) * 56 + j0 + qj) * CH + h * 32 + ch] = rne_bf16(oacc[j]);
    }
}

// final LayerNorm over 512, 4 rows/block, write f32
__global__ __launch_bounds__(256) void ln512_out_kernel(const float* __restrict__ in,
    const float* __restrict__ g, const float* __restrict__ b, float* __restrict__ out)
{
    int w = threadIdx.x >> 6, lane = threadIdx.x & 63;
    int p = blockIdx.x * 4 + w;
    const float4* ip = reinterpret_cast<const float4*>(in + (size_t)p * 512);
    float4 v0 = ip[lane * 2], v1 = ip[lane * 2 + 1];
    float vals[8] = { v0.x, v0.y, v0.z, v0.w, v1.x, v1.y, v1.z, v1.w };
    float s = 0.f, sq = 0.f;
#pragma unroll
    for (int q = 0; q < 8; ++q) { s += vals[q]; sq += vals[q] * vals[q]; }
#pragma unroll
    for (int o = 32; o > 0; o >>= 1) { s += __shfl_xor(s, o); sq += __shfl_xor(sq, o); }
    float mean = s * (1.0f / 512.0f);
    float inv = rsqrtf(sq * (1.0f / 512.0f) - mean * mean + 1e-5f);
#pragma unroll
    for (int q = 0; q < 8; ++q) {
        int c = lane * 8 + q;
        out[(size_t)p * 512 + c] = (vals[q] - mean) * inv * g[c] + b[c];
    }
}

extern "C" void kernel_launch(void* const* d_in, const int* in_sizes, int n_in,
                              void* d_out, int out_size, void* d_ws, size_t ws_size,
                              hipStream_t stream)
{
    const float* X      = (const float*)d_in[0];
    const float* XM     = (const float*)d_in[1];
    const float* sa_n1g = (const float*)d_in[2];
    const float* sa_n1b = (const float*)d_in[3];
    const float* sa_qkvw= (const float*)d_in[4];
    const float* sa_qkvb= (const float*)d_in[5];
    const float* sa_rpb = (const float*)d_in[6];
    const float* sa_pw  = (const float*)d_in[7];
    const float* sa_pb  = (const float*)d_in[8];
    const float* sa_n2g = (const float*)d_in[9];
    const float* sa_n2b = (const float*)d_in[10];
    const float* sa_f1w = (const float*)d_in[11];
    const float* sa_f1b = (const float*)d_in[12];
    const float* sa_f2w = (const float*)d_in[13];
    const float* sa_f2b = (const float*)d_in[14];
    const float* cr_n1g = (const float*)d_in[15];
    const float* cr_n1b = (const float*)d_in[16];
    const float* cr_qw  = (const float*)d_in[17];
    const float* cr_qb  = (const float*)d_in[18];
    const float* cr_kvw = (const float*)d_in[19];
    const float* cr_kvb = (const float*)d_in[20];
    const float* cr_rpb = (const float*)d_in[21];
    const float* cr_pw  = (const float*)d_in[22];
    const float* cr_pb  = (const float*)d_in[23];
    const float* cr_n2g = (const float*)d_in[24];
    const float* cr_n2b = (const float*)d_in[25];
    const float* cr_f1w = (const float*)d_in[26];
    const float* cr_f1b = (const float*)d_in[27];
    const float* cr_f2w = (const float*)d_in[28];
    const float* cr_f2b = (const float*)d_in[29];
    const float* dconvw = (const float*)d_in[30];
    const float* ds_ng  = (const float*)d_in[31];
    const float* ds_nb  = (const float*)d_in[32];

    const size_t NC = (size_t)NPIX * CH;       // 1,605,632
    float* ws   = (float*)d_ws;
    float* xb   = ws;                          // [NPIX,128] f32 x state
    float* xcb  = xb + NC;                     // [NPIX,128] f32 x_cross state (first written by CR proj)
    float* bigR = xcb + NC;                    // 2NC f32 region
    u16* bigb   = (u16*)bigR;                  // [NPIX,512] bf16: CR kv (stage1/NA) then SA fc1 out
    u16* hnb    = (u16*)(bigR + 2 * NC);       // [NPIX,128] bf16: CR NA out
    u16* attnb  = hnb + NC;                    // [NPIX,128] bf16: SA NA out
    u16* xcbbf  = attnb + NC;                  // [NPIX,128] bf16 mirror of xcb state
    u16* xbbf   = xcbbf + NC;                  // [NPIX,128] bf16 mirror of xb (for conv)
    u16* qkvb   = xbbf + NC;                   // [NPIX,384] bf16 SA qkv; with bufQb = CR fc1 out region
    u16* bufQb  = qkvb + (size_t)NPIX * 384;   // [NPIX,128] bf16 CR q
    u16* wa     = bufQb + NC;                  // bf16 weight arena
    u16* kvb    = bigb;                        // [NPIX,256] CR kv (time-disjoint alias)
    u16* bigcr  = qkvb;                        // [NPIX,512] CR fc1 out (time-disjoint alias of qkvb+bufQb)

    // ---- weight arena layout + transpose descriptors ----
    TPack tp;
    int tile = 0, idx = 0;
    u16* p = wa;
    u16* qkvt[2]; u16* pwt[2]; u16* f1t[2]; u16* f2t[2];
    u16* qt[2];   u16* kvt[2]; u16* cpt[2]; u16* cf1t[2];
    u16* cf2t[2]; u16* convt;
    auto add = [&](const float* s, u16*& dst, int K, int N) {
        dst = p;
        tp.d[idx].src = s; tp.d[idx].dst = p; tp.d[idx].K = K; tp.d[idx].N = N; tp.d[idx].tile0 = tile;
        tile += (K / 32) * (N / 32); p += (size_t)K * N; ++idx;
    };
    for (int l = 0; l < 2; ++l) add(sa_qkvw + (size_t)l * 128 * 384, qkvt[l], 128, 384);
    for (int l = 0; l < 2; ++l) add(sa_pw   + (size_t)l * 128 * 128, pwt[l],  128, 128);
    for (int l = 0; l < 2; ++l) add(sa_f1w  + (size_t)l * 128 * 512, f1t[l],  128, 512);
    for (int l = 0; l < 2; ++l) add(sa_f2w  + (size_t)l * 512 * 128, f2t[l],  512, 128);
    for (int l = 0; l < 2; ++l) add(cr_qw   + (size_t)l * 128 * 128, qt[l],   128, 128);
    for (int l = 0; l < 2; ++l) add(cr_kvw  + (size_t)l * 128 * 256, kvt[l],  128, 256);
    for (int l = 0; l < 2; ++l) add(cr_pw   + (size_t)l * 128 * 128, cpt[l],  128, 128);
    for (int l = 0; l < 2; ++l) add(cr_f1w  + (size_t)l * 128 * 512, cf1t[l], 128, 512);
    for (int l = 0; l < 2; ++l) add(cr_f2w  + (size_t)l * 512 * 128, cf2t[l], 512, 128);
    add(dconvw, convt, 2304, 512);

    const int n4 = NPIX * CH / 4;
    const int ndup = (n4 + 255) / 256;
    prep_kernel<<<tile + ndup, 256, 0, stream>>>(tp, tile, X, xb, xcbbf, n4);

    for (int l = 0; l < 2; ++l) {
        stage1_kernel<<<1764, 256, 0, stream>>>(
            xb, qkvt[l], sa_n1g + l * CH, sa_n1b + l * CH, sa_qkvb + l * 384, qkvb,
            xcbbf, qt[l], cr_qb + l * CH, bufQb,
            XM, kvt[l], cr_n1g + l * CH, cr_n1b + l * CH, cr_kvb + l * 256, kvb);
        na2_kernel<<<dim3(392, 8), 256, 0, stream>>>(
            qkvb, 384, qkvb + 128, qkvb + 256, 384, sa_rpb + l * HEADS * 169, attnb,
            bufQb, 128, kvb, kvb + 128, 256, cr_rpb + l * HEADS * 169, hnb);
        proj_kernel<<<dim3(784, 2), 256, 0, stream>>>(
            attnb, pwt[l], sa_pb + l * CH, xb, xb,
            hnb, cpt[l], cr_pb + l * CH, XM, xcb);
        fc1_kernel<<<dim3(392, 4), 256, 0, stream>>>(
            xb, f1t[l], sa_n2g + l * CH, sa_n2b + l * CH, sa_f1b + l * HID, bigb,
            xcb, cf1t[l], cr_n2g + l * CH, cr_n2b + l * CH, cr_f1b + l * HID, bigcr);
        fc2_kernel<<<dim3(784, 2), 256, 0, stream>>>(
            bigb, f2t[l], sa_f2b + l * CH, xb, xb, xbbf,
            bigcr, cf2t[l], cr_f2b + l * CH, xcb, xcb, xcbbf);
    }

    // ---- downsample conv (MFMA implicit GEMM) + final LN ----
    conv_mfma_kernel<<<dim3(3136 / 32, 512 / 64), 256, 0, stream>>>(xbbf, xcbbf, convt, bigR);
    ln512_out_kernel<<<3136 / 4, 256, 0, stream>>>(bigR, ds_ng, ds_nb, (float*)d_out);
}